// Round 1
// baseline (812.924 us; speedup 1.0000x reference)
//
#include <hip/hip_runtime.h>
#include <stdint.h>

#define NN 100000
#define NE 1600000
#define FIN 602
#define KP1 608      // 19 * 32, zero-padded K for layer-1 GEMM
#define H 256
#define C 42
#define NP2 48       // padded N for layer-2 GEMM (3 tiles of 16)
#define NB1 98       // ceil(NN / 1024) scan blocks
#define LDA1 40      // padded LDS row stride (elements) for gemm1 staging tiles
#define LDA2 40      // padded LDS row stride (elements) for gemm2 staging tiles

typedef __bf16 bf16;
typedef __bf16 bf16x8 __attribute__((ext_vector_type(8)));
typedef float f32x4 __attribute__((ext_vector_type(4)));

__device__ __forceinline__ float b2f(bf16 v) { return (float)v; }
__device__ __forceinline__ bf16 f2b(float v) { return (bf16)v; }
__device__ __forceinline__ float us2f(unsigned short u) {
    union { unsigned int i; float f; } w; w.i = ((unsigned int)u) << 16; return w.f;
}

// ---------------- CSR build ----------------

__global__ void k_zero(int* __restrict__ p, int n) {
    int i = blockIdx.x * 256 + threadIdx.x;
    if (i < n) p[i] = 0;
}

__global__ void k_count(const int* __restrict__ dst, int* __restrict__ cnt) {
    int e = blockIdx.x * 256 + threadIdx.x;
    if (e < NE) atomicAdd(&cnt[dst[e]], 1);
}

__global__ void k_dinv(const int* __restrict__ cnt, float* __restrict__ dinv) {
    int i = blockIdx.x * 256 + threadIdx.x;
    if (i < NN) dinv[i] = rsqrtf((float)(cnt[i] + 1));  // +1 self loop
}

__global__ __launch_bounds__(256) void k_scan1(const int* __restrict__ cnt,
                                               int* __restrict__ excl, int* __restrict__ bsum) {
    __shared__ int ts[256];
    const int tid = threadIdx.x;
    const int base = blockIdx.x * 1024 + tid * 4;
    int v[4];
#pragma unroll
    for (int j = 0; j < 4; ++j) v[j] = (base + j < NN) ? cnt[base + j] : 0;
    int s = v[0] + v[1] + v[2] + v[3];
    ts[tid] = s;
    __syncthreads();
    for (int off = 1; off < 256; off <<= 1) {
        int t = (tid >= off) ? ts[tid - off] : 0;
        __syncthreads();
        if (tid >= off) ts[tid] += t;
        __syncthreads();
    }
    int prefix = ts[tid] - s;
    if (tid == 255) bsum[blockIdx.x] = ts[255];
    int run = prefix;
#pragma unroll
    for (int j = 0; j < 4; ++j) {
        if (base + j < NN) excl[base + j] = run;
        run += v[j];
    }
}

__global__ __launch_bounds__(128) void k_scan2(int* __restrict__ bsum) {
    __shared__ int ts[128];
    const int tid = threadIdx.x;
    int v = (tid < NB1) ? bsum[tid] : 0;
    ts[tid] = v;
    __syncthreads();
    for (int off = 1; off < 128; off <<= 1) {
        int t = (tid >= off) ? ts[tid - off] : 0;
        __syncthreads();
        if (tid >= off) ts[tid] += t;
        __syncthreads();
    }
    if (tid < NB1) bsum[tid] = ts[tid] - v;
}

__global__ __launch_bounds__(256) void k_scan3(const int* __restrict__ excl, const int* __restrict__ bsum,
                                               int* __restrict__ rowptr, int* __restrict__ cursor) {
    const int tid = threadIdx.x;
    const int base = blockIdx.x * 1024 + tid * 4;
    const int add = bsum[blockIdx.x];
#pragma unroll
    for (int j = 0; j < 4; ++j) {
        int i = base + j;
        if (i < NN) { int r = excl[i] + add; rowptr[i] = r; cursor[i] = r; }
    }
    if (blockIdx.x == 0 && tid == 0) rowptr[NN] = NE;
}

__global__ void k_fill(const int* __restrict__ src, const int* __restrict__ dst,
                       int* __restrict__ cursor, int* __restrict__ esrc) {
    int e = blockIdx.x * 256 + threadIdx.x;
    if (e < NE) {
        int d = dst[e];
        int pos = atomicAdd(&cursor[d], 1);
        esrc[pos] = src[e];
    }
}

// ---------------- weight transposes + fp32->bf16 convert ----------------

__global__ void k_transpose_w1(const float* __restrict__ w1, bf16* __restrict__ w1t) {
    int idx = blockIdx.x * 256 + threadIdx.x;  // grid covers 256*608 exactly
    int n = idx / KP1;
    int k = idx % KP1;
    w1t[idx] = (k < FIN) ? f2b(w1[(size_t)k * H + n]) : (bf16)0.0f;
}

__global__ void k_transpose_w2(const float* __restrict__ w2, bf16* __restrict__ w2t) {
    int idx = blockIdx.x * 256 + threadIdx.x;  // grid covers 48*256 exactly
    int n = idx >> 8;
    int k = idx & 255;
    w2t[idx] = (n < C) ? f2b(w2[(size_t)k * C + n]) : (bf16)0.0f;
}

// ---------------- GEMM1: h1[NN][256] = bf16(x)[NN][602] @ bf16(W1) ----------------
// 64-row tile, reg-prefetched (2 K-steps deep) + double-buffered LDS.
// One RAW s_barrier per K-step; lgkmcnt(0) drained before each barrier; vmcnt is
// NEVER drained in the loop (the x loads for step kk+2 stay in flight across
// barriers — this removes the per-step vmcnt(0) barrier-drain that left the
// matrix pipe 91% idle in the previous version).
// LDS row stride padded 32 -> 40 elems (80 B) to break the 8-way ds_read_b128
// bank conflict (64 B stride put all even rows on banks 0-3).
// A-frag: lane(q=lane>>4, r=lane&15) holds A[m=r][k=q*8+j]; C/D: col=r, row=q*4+reg.

__device__ __forceinline__ void g1_load(const float* xrow, int kk, int sseg, float2 rx[4]) {
    const int k0 = kk * 32;
    const int c0 = k0 + sseg * 8;
    if (c0 + 8 <= FIN) {
        // 8B-aligned float2 loads (row byte offset mult of 8)
        const float2* p = (const float2*)(xrow + k0);
        rx[0] = p[0]; rx[1] = p[1]; rx[2] = p[2]; rx[3] = p[3];
    } else {
        float t[8];
#pragma unroll
        for (int j = 0; j < 8; ++j) t[j] = (c0 + j < FIN) ? xrow[k0 + j] : 0.f;
        rx[0] = make_float2(t[0], t[1]);
        rx[1] = make_float2(t[2], t[3]);
        rx[2] = make_float2(t[4], t[5]);
        rx[3] = make_float2(t[6], t[7]);
    }
}

__device__ __forceinline__ void g1_step(int kk, const float* xrow, float2 rx[4],
                                        bf16* buf, int srow, int sseg, int q, int r,
                                        const bf16* bbase, f32x4 acc[4][4], bool prefetch) {
    // convert + stage current K-chunk (regs were loaded 2 steps ago)
    union { bf16 s[8]; uint4 u; } pk;
    pk.s[0] = f2b(rx[0].x); pk.s[1] = f2b(rx[0].y);
    pk.s[2] = f2b(rx[1].x); pk.s[3] = f2b(rx[1].y);
    pk.s[4] = f2b(rx[2].x); pk.s[5] = f2b(rx[2].y);
    pk.s[6] = f2b(rx[3].x); pk.s[7] = f2b(rx[3].y);
    *(uint4*)(buf + srow * LDA1 + sseg * 8) = pk.u;
    // issue the kk+2 global loads now: they hide under ~2 K-steps of compute
    if (prefetch) g1_load(xrow, kk + 2, sseg, rx);
    // drain own LDS ops only; vmcnt stays outstanding across the barrier
    asm volatile("s_waitcnt lgkmcnt(0)" ::: "memory");
    __builtin_amdgcn_s_barrier();

    const int k0 = kk * 32;
    bf16x8 af[4];
#pragma unroll
    for (int rt = 0; rt < 4; ++rt) {
        union { uint4 u; bf16x8 v; } ua;
        ua.u = *(const uint4*)(buf + (rt * 16 + r) * LDA1 + q * 8);
        af[rt] = ua.v;
    }
#pragma unroll
    for (int ct = 0; ct < 4; ++ct) {
        const bf16* bp = bbase + (size_t)(ct * 16 + r) * KP1 + k0 + q * 8;
        union { uint4 u; bf16x8 v; } ub;
        ub.u = *(const uint4*)bp;
#pragma unroll
        for (int rt = 0; rt < 4; ++rt)
            acc[rt][ct] = __builtin_amdgcn_mfma_f32_16x16x32_bf16(af[rt], ub.v, acc[rt][ct], 0, 0, 0);
    }
}

__global__ __launch_bounds__(256) void k_gemm1(const float* __restrict__ x,
                                               const bf16* __restrict__ w1t,
                                               bf16* __restrict__ h1) {
    __shared__ bf16 As0[64 * LDA1];  // 5 KB each, double-buffered
    __shared__ bf16 As1[64 * LDA1];
    const int tid = threadIdx.x;
    const int wave = tid >> 6;
    const int lane = tid & 63;
    const int q = lane >> 4;
    const int r = lane & 15;
    const int row0 = blockIdx.x * 64;

    // staging: thread t -> row (t>>2), 8-float segment (t&3)
    const int srow = tid >> 2;
    const int sseg = tid & 3;
    int gsrow = row0 + srow;
    if (gsrow >= NN) gsrow = NN - 1;  // clamp; stores guarded
    const float* xrow = x + (size_t)gsrow * FIN + sseg * 8;

    f32x4 acc[4][4];  // [row-tile][col-tile]
#pragma unroll
    for (int a = 0; a < 4; ++a)
#pragma unroll
        for (int b = 0; b < 4; ++b) acc[a][b] = (f32x4){0.f, 0.f, 0.f, 0.f};

    const bf16* bbase = w1t + (size_t)(wave * 64) * KP1;

    float2 ra[4], rb[4];
    g1_load(xrow, 0, sseg, ra);
    g1_load(xrow, 1, sseg, rb);

#pragma unroll 1
    for (int kk = 0; kk < 19; kk += 2) {
        g1_step(kk, xrow, ra, As0, srow, sseg, q, r, bbase, acc, kk + 2 < 19);
        if (kk + 1 < 19)
            g1_step(kk + 1, xrow, rb, As1, srow, sseg, q, r, bbase, acc, kk + 3 < 19);
    }

#pragma unroll
    for (int rt = 0; rt < 4; ++rt) {
#pragma unroll
        for (int ct = 0; ct < 4; ++ct) {
            const int col = wave * 64 + ct * 16 + r;
#pragma unroll
            for (int rr = 0; rr < 4; ++rr) {
                const int m = row0 + rt * 16 + q * 4 + rr;
                if (m < NN) h1[(size_t)m * H + col] = f2b(acc[rt][ct][rr]);
            }
        }
    }
}

// ---------------- layer-1 pull aggregation + bias + relu (fused) ----------------

__global__ __launch_bounds__(64) void k_gather1(const int* __restrict__ rowptr,
                                                const int* __restrict__ esrc,
                                                const bf16* __restrict__ h1,
                                                const float* __restrict__ dinv,
                                                const float* __restrict__ b1,
                                                bf16* __restrict__ hb) {
    const int n = blockIdx.x;
    const int tid = threadIdx.x;
    const float dn = dinv[n];

    uint2 u = ((const uint2*)(h1 + (size_t)n * H))[tid];
    float ws = dn * dn;
    float a0 = us2f((unsigned short)(u.x & 0xffff)) * ws;
    float a1 = us2f((unsigned short)(u.x >> 16)) * ws;
    float a2 = us2f((unsigned short)(u.y & 0xffff)) * ws;
    float a3 = us2f((unsigned short)(u.y >> 16)) * ws;

    const int beg = rowptr[n], end = rowptr[n + 1];
    int j = beg;
    // unroll-by-4: 4 independent load chains in flight
    for (; j + 3 < end; j += 4) {
        int s0 = esrc[j], s1 = esrc[j + 1], s2 = esrc[j + 2], s3 = esrc[j + 3];
        float w0 = dinv[s0] * dn, w1 = dinv[s1] * dn, w2 = dinv[s2] * dn, w3 = dinv[s3] * dn;
        uint2 v0 = ((const uint2*)(h1 + (size_t)s0 * H))[tid];
        uint2 v1 = ((const uint2*)(h1 + (size_t)s1 * H))[tid];
        uint2 v2 = ((const uint2*)(h1 + (size_t)s2 * H))[tid];
        uint2 v3 = ((const uint2*)(h1 + (size_t)s3 * H))[tid];
        a0 += us2f((unsigned short)(v0.x & 0xffff)) * w0;
        a1 += us2f((unsigned short)(v0.x >> 16)) * w0;
        a2 += us2f((unsigned short)(v0.y & 0xffff)) * w0;
        a3 += us2f((unsigned short)(v0.y >> 16)) * w0;
        a0 += us2f((unsigned short)(v1.x & 0xffff)) * w1;
        a1 += us2f((unsigned short)(v1.x >> 16)) * w1;
        a2 += us2f((unsigned short)(v1.y & 0xffff)) * w1;
        a3 += us2f((unsigned short)(v1.y >> 16)) * w1;
        a0 += us2f((unsigned short)(v2.x & 0xffff)) * w2;
        a1 += us2f((unsigned short)(v2.x >> 16)) * w2;
        a2 += us2f((unsigned short)(v2.y & 0xffff)) * w2;
        a3 += us2f((unsigned short)(v2.y >> 16)) * w2;
        a0 += us2f((unsigned short)(v3.x & 0xffff)) * w3;
        a1 += us2f((unsigned short)(v3.x >> 16)) * w3;
        a2 += us2f((unsigned short)(v3.y & 0xffff)) * w3;
        a3 += us2f((unsigned short)(v3.y >> 16)) * w3;
    }
    for (; j < end; ++j) {
        int s = esrc[j];
        float w = dinv[s] * dn;
        uint2 v = ((const uint2*)(h1 + (size_t)s * H))[tid];
        a0 += us2f((unsigned short)(v.x & 0xffff)) * w;
        a1 += us2f((unsigned short)(v.x >> 16)) * w;
        a2 += us2f((unsigned short)(v.y & 0xffff)) * w;
        a3 += us2f((unsigned short)(v.y >> 16)) * w;
    }

    float4 bb = ((const float4*)b1)[tid];
    a0 += bb.x; a1 += bb.y; a2 += bb.z; a3 += bb.w;
    a0 = a0 > 0.f ? a0 : 0.f;
    a1 = a1 > 0.f ? a1 : 0.f;
    a2 = a2 > 0.f ? a2 : 0.f;
    a3 = a3 > 0.f ? a3 : 0.f;

    union { unsigned short s[4]; uint2 u; } pk;
    union { bf16 b; unsigned short s; } cv;
    cv.b = f2b(a0); pk.s[0] = cv.s;
    cv.b = f2b(a1); pk.s[1] = cv.s;
    cv.b = f2b(a2); pk.s[2] = cv.s;
    cv.b = f2b(a3); pk.s[3] = cv.s;
    ((uint2*)(hb + (size_t)n * H))[tid] = pk.u;
}

// ---------------- GEMM2: h2[NN][42] = hb[NN][256] @ W2 ----------------
// 128-row tile (grid 782 -> ~3 blocks/CU vs 1.5 before), same 2-deep
// reg-prefetch + LDS dbuf + raw-barrier template as gemm1.
// wave w covers rows [w*32, +32) (2 row-tiles), 3 col-tiles.

__device__ __forceinline__ void g2_load(const bf16* arow, int kk, uint4 rx[2]) {
    const bf16* p = arow + kk * 32;
    rx[0] = *(const uint4*)p;
    rx[1] = *(const uint4*)(p + 8);
}

__device__ __forceinline__ void g2_step(int kk, const bf16* arow, uint4 rx[2],
                                        bf16* buf, int srow, int sseg, int q, int r, int wave,
                                        const bf16* w2t, f32x4 acc[2][3], bool prefetch) {
    *(uint4*)(buf + srow * LDA2 + sseg * 16) = rx[0];
    *(uint4*)(buf + srow * LDA2 + sseg * 16 + 8) = rx[1];
    if (prefetch) g2_load(arow, kk + 2, rx);
    asm volatile("s_waitcnt lgkmcnt(0)" ::: "memory");
    __builtin_amdgcn_s_barrier();

    const int k0 = kk * 32;
    bf16x8 af[2];
#pragma unroll
    for (int rt = 0; rt < 2; ++rt) {
        union { uint4 u; bf16x8 v; } ua;
        ua.u = *(const uint4*)(buf + (wave * 32 + rt * 16 + r) * LDA2 + q * 8);
        af[rt] = ua.v;
    }
#pragma unroll
    for (int ct = 0; ct < 3; ++ct) {
        const bf16* bp = w2t + (size_t)(ct * 16 + r) * H + k0 + q * 8;
        union { uint4 u; bf16x8 v; } ub;
        ub.u = *(const uint4*)bp;
#pragma unroll
        for (int rt = 0; rt < 2; ++rt)
            acc[rt][ct] = __builtin_amdgcn_mfma_f32_16x16x32_bf16(af[rt], ub.v, acc[rt][ct], 0, 0, 0);
    }
}

__global__ __launch_bounds__(256) void k_gemm2(const bf16* __restrict__ hb,
                                               const bf16* __restrict__ w2t,
                                               bf16* __restrict__ h2) {
    __shared__ bf16 As0[128 * LDA2];  // 10 KB each, double-buffered
    __shared__ bf16 As1[128 * LDA2];
    const int tid = threadIdx.x;
    const int wave = tid >> 6;
    const int lane = tid & 63;
    const int q = lane >> 4;
    const int r = lane & 15;
    const int row0 = blockIdx.x * 128;

    // staging: thread t -> row (t>>1), 16-elem segment (t&1)
    const int srow = tid >> 1;
    const int sseg = tid & 1;
    int gsrow = row0 + srow;
    if (gsrow >= NN) gsrow = NN - 1;
    const bf16* arow = hb + (size_t)gsrow * H + sseg * 16;

    f32x4 acc[2][3];
#pragma unroll
    for (int a = 0; a < 2; ++a)
#pragma unroll
        for (int b = 0; b < 3; ++b) acc[a][b] = (f32x4){0.f, 0.f, 0.f, 0.f};

    uint4 ra[2], rb[2];
    g2_load(arow, 0, ra);
    g2_load(arow, 1, rb);

#pragma unroll 1
    for (int kk = 0; kk < 8; kk += 2) {
        g2_step(kk, arow, ra, As0, srow, sseg, q, r, wave, w2t, acc, kk + 2 < 8);
        g2_step(kk + 1, arow, rb, As1, srow, sseg, q, r, wave, w2t, acc, kk + 3 < 8);
    }

#pragma unroll
    for (int rt = 0; rt < 2; ++rt) {
#pragma unroll
        for (int ct = 0; ct < 3; ++ct) {
            const int col = ct * 16 + r;
            if (col < C) {
#pragma unroll
                for (int rr = 0; rr < 4; ++rr) {
                    const int m = row0 + wave * 32 + rt * 16 + q * 4 + rr;
                    if (m < NN) h2[(size_t)m * C + col] = f2b(acc[rt][ct][rr]);
                }
            }
        }
    }
}

// ---------------- layer-2 pull aggregation + bias + log_softmax (fused) ----------------

__global__ __launch_bounds__(64) void k_gather2(const int* __restrict__ rowptr,
                                                const int* __restrict__ esrc,
                                                const bf16* __restrict__ h2,
                                                const float* __restrict__ dinv,
                                                const float* __restrict__ b2,
                                                float* __restrict__ out) {
    const int n = blockIdx.x;
    const int c = threadIdx.x;
    const float dn = dinv[n];

    float acc = 0.f;
    if (c < C) acc = b2f(h2[(size_t)n * C + c]) * dn * dn;

    const int beg = rowptr[n], end = rowptr[n + 1];
    int j = beg;
    for (; j + 3 < end; j += 4) {
        int s0 = esrc[j], s1 = esrc[j + 1], s2 = esrc[j + 2], s3 = esrc[j + 3];
        float w0 = dinv[s0] * dn, w1 = dinv[s1] * dn, w2 = dinv[s2] * dn, w3 = dinv[s3] * dn;
        if (c < C) {
            float v0 = b2f(h2[(size_t)s0 * C + c]);
            float v1 = b2f(h2[(size_t)s1 * C + c]);
            float v2 = b2f(h2[(size_t)s2 * C + c]);
            float v3 = b2f(h2[(size_t)s3 * C + c]);
            acc += v0 * w0 + v1 * w1 + v2 * w2 + v3 * w3;
        }
    }
    for (; j < end; ++j) {
        int s = esrc[j];
        float w = dinv[s] * dn;
        if (c < C) acc += b2f(h2[(size_t)s * C + c]) * w;
    }

    float v = (c < C) ? acc + b2[c] : -INFINITY;
    float m = v;
#pragma unroll
    for (int o = 32; o > 0; o >>= 1) m = fmaxf(m, __shfl_xor(m, o, 64));
    float ex = (c < C) ? expf(v - m) : 0.f;
    float s = ex;
#pragma unroll
    for (int o = 32; o > 0; o >>= 1) s += __shfl_xor(s, o, 64);
    if (c < C) out[(size_t)n * C + c] = (v - m) - logf(s);
}

// ---------------- launch ----------------

extern "C" void kernel_launch(void* const* d_in, const int* in_sizes, int n_in,
                              void* d_out, int out_size, void* d_ws, size_t ws_size,
                              hipStream_t stream) {
    const float* x  = (const float*)d_in[0];  // fp32 [NN][602]
    const int*   ei = (const int*)d_in[1];    // int32 [2][NE]
    const float* w1 = (const float*)d_in[2];  // fp32 [602][256]
    const float* b1 = (const float*)d_in[3];  // fp32 [256]
    const float* w2 = (const float*)d_in[4];  // fp32 [256][42]
    const float* b2 = (const float*)d_in[5];  // fp32 [42]
    float* out = (float*)d_out;               // fp32 [NN][42]

    const int* src = ei;
    const int* dst = ei + NE;

    char* base = (char*)d_ws;
    size_t off = 0;
    auto alloc = [&](size_t bytes) -> void* {
        void* p = base + off;
        off += (bytes + 255) & ~(size_t)255;
        return p;
    };
    int*   cnt    = (int*)alloc((size_t)NN * 4);
    float* dinv   = (float*)alloc((size_t)NN * 4);
    int*   excl   = (int*)alloc((size_t)NN * 4);
    int*   bsum   = (int*)alloc(128 * 4);
    int*   rowptr = (int*)alloc((size_t)(NN + 1) * 4);
    int*   cursor = (int*)alloc((size_t)NN * 4);
    int*   esrc   = (int*)alloc((size_t)NE * 4);
    bf16*  w1t    = (bf16*)alloc((size_t)H * KP1 * 2);
    bf16*  w2t    = (bf16*)alloc((size_t)NP2 * H * 2);
    bf16*  h1     = (bf16*)alloc((size_t)NN * H * 2);
    bf16*  hb     = (bf16*)alloc((size_t)NN * H * 2);
    bf16*  h2     = (bf16*)alloc((size_t)NN * C * 2);
    (void)ws_size;

    // CSR build + norm
    k_zero<<<dim3((NN + 255) / 256), dim3(256), 0, stream>>>(cnt, NN);
    k_count<<<dim3((NE + 255) / 256), dim3(256), 0, stream>>>(dst, cnt);
    k_dinv<<<dim3((NN + 255) / 256), dim3(256), 0, stream>>>(cnt, dinv);
    k_scan1<<<dim3(NB1), dim3(256), 0, stream>>>(cnt, excl, bsum);
    k_scan2<<<dim3(1), dim3(128), 0, stream>>>(bsum);
    k_scan3<<<dim3(NB1), dim3(256), 0, stream>>>(excl, bsum, rowptr, cursor);
    k_fill<<<dim3((NE + 255) / 256), dim3(256), 0, stream>>>(src, dst, cursor, esrc);

    // weights
    k_transpose_w1<<<dim3(KP1), dim3(256), 0, stream>>>(w1, w1t);
    k_transpose_w2<<<dim3(NP2), dim3(256), 0, stream>>>(w2, w2t);

    // layer 1
    k_gemm1<<<dim3((NN + 63) / 64), dim3(256), 0, stream>>>(x, w1t, h1);
    k_gather1<<<dim3(NN), dim3(64), 0, stream>>>(rowptr, esrc, h1, dinv, b1, hb);

    // layer 2
    k_gemm2<<<dim3((NN + 127) / 128), dim3(256), 0, stream>>>(hb, w2t, h2);
    k_gather2<<<dim3(NN), dim3(64), 0, stream>>>(rowptr, esrc, h2, dinv, b2, out);
}